// Round 2
// baseline (988.187 us; speedup 1.0000x reference)
//
#include <hip/hip_runtime.h>

typedef _Float16 f16;
typedef __attribute__((ext_vector_type(8))) _Float16 f16x8;
typedef __attribute__((ext_vector_type(4))) float f32x4;

#define BT   131072
#define DD   512
#define TM   32
#define MEFF 96
#define NBLK (BT / TM)  // 4096

__device__ __forceinline__ float softplus20(float z) {
    // softplus(20z)/20 = max(z,0) + log1p(exp(-20|z|))/20
    float a = fabsf(z);
    float e = __expf(-20.f * a);
    return fmaxf(z, 0.f) + __logf(1.f + e) * 0.05f;
}

// swizzled LDS fp16 tile: byte = row*1024 + (colbyte ^ ((row&7)<<4))
__device__ __forceinline__ void stA(char* ab, int row, int colbyte, float v) {
    *(f16*)(ab + row * 1024 + (colbyte ^ ((row & 7) << 4))) = (f16)v;
}
__device__ __forceinline__ f16x8 ldA8(const char* ab, int row, int kbyte) {
    return *(const f16x8*)(ab + row * 1024 + (kbyte ^ ((row & 7) << 4)));
}

// Pack W1..W3 (512x512 fp32 row-major) into MFMA B-fragment order fp16:
// frag f = (l*16+sk)*32 + nsub ; lane l: n = nsub*16+(lane&15), k = sk*32+(lane>>4)*8 .. +8
__global__ void prep_w(const float* __restrict__ W1, const float* __restrict__ W2,
                       const float* __restrict__ W3, f16* __restrict__ wp) {
    int tid = blockIdx.x * 256 + threadIdx.x;
    if (tid >= 3 * 16 * 32 * 64) return;
    int lane = tid & 63;
    int frag = tid >> 6;
    int nsub = frag & 31;
    int sk   = (frag >> 5) & 15;
    int l    = frag >> 9;
    const float* W = (l == 0) ? W1 : (l == 1) ? W2 : W3;
    int n = nsub * 16 + (lane & 15);
    int k = sk * 32 + (lane >> 4) * 8;
    const float* p = W + n * DD + k;
    f16x8 o;
    #pragma unroll
    for (int j = 0; j < 8; ++j) o[j] = (f16)p[j];
    ((f16x8*)wp)[tid] = o;
}

template<bool PREP>
__global__ __launch_bounds__(512, 1) void mlp_fused(
    const float* __restrict__ tx,
    const float* __restrict__ W0, const float* __restrict__ b0v,
    const float* __restrict__ W1, const float* __restrict__ b1v,
    const float* __restrict__ W2, const float* __restrict__ b2v,
    const float* __restrict__ W3, const float* __restrict__ b3v,
    const float* __restrict__ W4, const float* __restrict__ b4v,
    const f16* __restrict__ wp, float* __restrict__ out)
{
    __shared__ __align__(16) short abuf_s[MEFF * DD];  // 96 KB fp16, swizzled
    __shared__ float txb[TM * 3];
    char* ab = (char*)abuf_s;

    const int tid  = threadIdx.x;
    const int lane = tid & 63;
    const int wv   = tid >> 6;   // 0..7, owns cols [wv*64, wv*64+64)
    const int g16  = lane >> 4;
    const int l15  = lane & 15;
    const long s0  = (long)blockIdx.x * TM;

    if (tid < TM * 3) txb[tid] = tx[s0 * 3 + tid];
    __syncthreads();

    // ---- layer 0: z1 = W0 x + b0 (K=3, fp32 VALU); rows: h | sg*W0[:,1] | sg*W0[:,2]
    {
        int n = tid;  // one output neuron per thread
        float w0 = W0[n * 3 + 0], w1 = W0[n * 3 + 1], w2 = W0[n * 3 + 2], bb = b0v[n];
        #pragma unroll 4
        for (int s = 0; s < TM; ++s) {
            float z = fmaf(w0, txb[s * 3], fmaf(w1, txb[s * 3 + 1], fmaf(w2, txb[s * 3 + 2], bb)));
            float h = softplus20(z);
            float sg = 1.f - __expf(-20.f * h);  // sigmoid(20z) via softplus inverse
            stA(ab, s,          n * 2, h);
            stA(ab, TM + s,     n * 2, sg * w1);
            stA(ab, 2 * TM + s, n * 2, sg * w2);
        }
    }
    __syncthreads();

    float sgr[2][4][4];  // sigma regs: [h-msub][nsub][r]

    // ---- layers 1..3: fused GEMM over M_eff=96 rows (h + 2 tangents), N=K=512
    for (int l = 0; l < 3; ++l) {
        const float* Wl = (l == 0) ? W1 : (l == 1) ? W2 : W3;
        const float* bl = (l == 0) ? b1v : (l == 1) ? b2v : b3v;
        const f16x8* wpb = (const f16x8*)wp + (size_t)l * 16 * 32 * 64;

        f32x4 acc[6][4];
        #pragma unroll
        for (int m = 0; m < 6; ++m)
            #pragma unroll
            for (int n = 0; n < 4; ++n)
                acc[m][n] = f32x4{0.f, 0.f, 0.f, 0.f};

        auto loadA = [&](f16x8* dst, int sk) {
            #pragma unroll
            for (int m = 0; m < 6; ++m)
                dst[m] = ldA8(ab, m * 16 + l15, sk * 64 + g16 * 16);
        };
        auto loadB = [&](f16x8* dst, int sk) {
            if constexpr (PREP) {
                const f16x8* p = wpb + (size_t)(sk * 32 + wv * 4) * 64 + lane;
                #pragma unroll
                for (int n = 0; n < 4; ++n) dst[n] = p[n * 64];
            } else {
                #pragma unroll
                for (int n = 0; n < 4; ++n) {
                    const float* q = Wl + (size_t)(wv * 64 + n * 16 + l15) * DD + sk * 32 + g16 * 8;
                    float4 u0 = *(const float4*)q;
                    float4 u1 = *(const float4*)(q + 4);
                    f16x8 r;
                    r[0] = (f16)u0.x; r[1] = (f16)u0.y; r[2] = (f16)u0.z; r[3] = (f16)u0.w;
                    r[4] = (f16)u1.x; r[5] = (f16)u1.y; r[6] = (f16)u1.z; r[7] = (f16)u1.w;
                    dst[n] = r;
                }
            }
        };
        auto domfma = [&](f16x8* af, f16x8* bf) {
            #pragma unroll
            for (int m = 0; m < 6; ++m)
                #pragma unroll
                for (int n = 0; n < 4; ++n)
                    acc[m][n] = __builtin_amdgcn_mfma_f32_16x16x32_f16(af[m], bf[n], acc[m][n], 0, 0, 0);
        };

        // barrier-free k-loop, 2-stage software pipeline
        f16x8 a0[6], a1[6], bf0[4], bf1[4];
        loadA(a0, 0); loadB(bf0, 0);
        for (int sk = 0; sk < 16; sk += 2) {
            loadA(a1, sk + 1); loadB(bf1, sk + 1);
            domfma(a0, bf0);
            if (sk + 2 < 16) { loadA(a0, sk + 2); loadB(bf0, sk + 2); }
            domfma(a1, bf1);
        }

        __syncthreads();  // all waves done reading abuf

        float bias[4];
        #pragma unroll
        for (int n = 0; n < 4; ++n) bias[n] = bl[wv * 64 + n * 16 + l15];

        // h rows (msub 0,1): z -> h -> LDS ; sigma -> regs
        #pragma unroll
        for (int m = 0; m < 2; ++m)
            #pragma unroll
            for (int n = 0; n < 4; ++n)
                #pragma unroll
                for (int r = 0; r < 4; ++r) {
                    int row = m * 16 + g16 * 4 + r;
                    float z = acc[m][n][r] + bias[n];
                    float h = softplus20(z);
                    sgr[m][n][r] = 1.f - __expf(-20.f * h);
                    stA(ab, row, (wv * 64 + n * 16 + l15) * 2, h);
                }
        // tangent rows (msub 2..5): hdot = sigma * zdot  (no bias). Same lane/reg as its h.
        #pragma unroll
        for (int m = 2; m < 6; ++m)
            #pragma unroll
            for (int n = 0; n < 4; ++n)
                #pragma unroll
                for (int r = 0; r < 4; ++r) {
                    int row = m * 16 + g16 * 4 + r;
                    float v = sgr[m & 1][n][r] * acc[m][n][r];
                    stA(ab, row, (wv * 64 + n * 16 + l15) * 2, v);
                }
        __syncthreads();
    }

    // ---- final layer (fp32 VALU dots): p = W4[1].h4 + b4[1]; u = (sy_dot, -sx_dot)
    {
        const int kb = lane * 8;
        float wsr[8], wpr[8];
        #pragma unroll
        for (int j = 0; j < 8; ++j) { wsr[j] = W4[kb + j]; wpr[j] = W4[DD + kb + j]; }
        float bp = b4v[1];
        #pragma unroll
        for (int i = 0; i < 4; ++i) {
            int s = wv * 4 + i;
            f16x8 hh = ldA8(ab, s,      lane * 16);
            f16x8 hx = ldA8(ab, 32 + s, lane * 16);
            f16x8 hy = ldA8(ab, 64 + s, lane * 16);
            float dy = 0.f, dx = 0.f, dp = 0.f;
            #pragma unroll
            for (int j = 0; j < 8; ++j) {
                dy = fmaf(wsr[j], (float)hy[j], dy);
                dx = fmaf(wsr[j], (float)hx[j], dx);
                dp = fmaf(wpr[j], (float)hh[j], dp);
            }
            #pragma unroll
            for (int mk = 1; mk < 64; mk <<= 1) {
                dy += __shfl_xor(dy, mk);
                dx += __shfl_xor(dx, mk);
                dp += __shfl_xor(dp, mk);
            }
            if (lane == 0) {
                float* o = out + (s0 + s) * 3;
                o[0] = dy;        // ds/dy
                o[1] = -dx;       // -ds/dx
                o[2] = dp + bp;   // pressure
            }
        }
    }
}

extern "C" void kernel_launch(void* const* d_in, const int* in_sizes, int n_in,
                              void* d_out, int out_size, void* d_ws, size_t ws_size,
                              hipStream_t stream) {
    const float* tx = (const float*)d_in[0];
    const float* W0 = (const float*)d_in[1]; const float* b0 = (const float*)d_in[2];
    const float* W1 = (const float*)d_in[3]; const float* b1 = (const float*)d_in[4];
    const float* W2 = (const float*)d_in[5]; const float* b2 = (const float*)d_in[6];
    const float* W3 = (const float*)d_in[7]; const float* b3 = (const float*)d_in[8];
    const float* W4 = (const float*)d_in[9]; const float* b4 = (const float*)d_in[10];
    float* out = (float*)d_out;

    const size_t need = (size_t)3 * 512 * 512 * sizeof(f16);
    if (ws_size >= need) {
        f16* wp = (f16*)d_ws;
        prep_w<<<(3 * 16 * 32 * 64 + 255) / 256, 256, 0, stream>>>(W1, W2, W3, wp);
        mlp_fused<true><<<NBLK, 512, 0, stream>>>(tx, W0, b0, W1, b1, W2, b2, W3, b3, W4, b4, wp, out);
    } else {
        mlp_fused<false><<<NBLK, 512, 0, stream>>>(tx, W0, b0, W1, b1, W2, b2, W3, b3, W4, b4, nullptr, out);
    }
}

// Round 3
// 979.593 us; speedup vs baseline: 1.0088x; 1.0088x over previous
//
#include <hip/hip_runtime.h>

typedef _Float16 f16;
typedef __attribute__((ext_vector_type(8))) _Float16 f16x8;
typedef __attribute__((ext_vector_type(4))) float f32x4;

#define BT   131072
#define DD   512
#define TM   32
#define MEFF 96
#define NBLK (BT / TM)  // 4096

__device__ __forceinline__ float softplus20(float z) {
    // softplus(20z)/20 = max(z,0) + log1p(exp(-20|z|))/20
    float a = fabsf(z);
    float e = __expf(-20.f * a);
    return fmaxf(z, 0.f) + __logf(1.f + e) * 0.05f;
}

// swizzled LDS fp16 tile: byte = row*1024 + (colbyte ^ ((row&7)<<4))
__device__ __forceinline__ void stA(char* ab, int row, int colbyte, float v) {
    *(f16*)(ab + row * 1024 + (colbyte ^ ((row & 7) << 4))) = (f16)v;
}
__device__ __forceinline__ f16x8 ldA8(const char* ab, int row, int kbyte) {
    return *(const f16x8*)(ab + row * 1024 + (kbyte ^ ((row & 7) << 4)));
}

// Pack W1..W3 (512x512 fp32 row-major) into MFMA B-fragment order fp16:
// frag f = (l*16+sk)*32 + nsub ; lane l: n = nsub*16+(lane&15), k = sk*32+(lane>>4)*8 .. +8
__global__ void prep_w(const float* __restrict__ W1, const float* __restrict__ W2,
                       const float* __restrict__ W3, f16* __restrict__ wp) {
    int tid = blockIdx.x * 256 + threadIdx.x;
    if (tid >= 3 * 16 * 32 * 64) return;
    int lane = tid & 63;
    int frag = tid >> 6;
    int nsub = frag & 31;
    int sk   = (frag >> 5) & 15;
    int l    = frag >> 9;
    const float* W = (l == 0) ? W1 : (l == 1) ? W2 : W3;
    int n = nsub * 16 + (lane & 15);
    int k = sk * 32 + (lane >> 4) * 8;
    const float* p = W + n * DD + k;
    f16x8 o;
    #pragma unroll
    for (int j = 0; j < 8; ++j) o[j] = (f16)p[j];
    ((f16x8*)wp)[tid] = o;
}

template<bool PREP>
__global__ __launch_bounds__(512, 2) void mlp_fused(
    const float* __restrict__ tx,
    const float* __restrict__ W0, const float* __restrict__ b0v,
    const float* __restrict__ W1, const float* __restrict__ b1v,
    const float* __restrict__ W2, const float* __restrict__ b2v,
    const float* __restrict__ W3, const float* __restrict__ b3v,
    const float* __restrict__ W4, const float* __restrict__ b4v,
    const f16* __restrict__ wp, float* __restrict__ out)
{
    __shared__ __align__(16) short abuf_s[MEFF * DD];  // 96 KB fp16, swizzled
    __shared__ float txb[TM * 3];
    char* ab = (char*)abuf_s;

    const int tid  = threadIdx.x;
    const int lane = tid & 63;
    const int wv   = tid >> 6;   // 0..7, owns cols [wv*64, wv*64+64)
    const int g16  = lane >> 4;
    const int l15  = lane & 15;
    const long s0  = (long)blockIdx.x * TM;

    if (tid < TM * 3) txb[tid] = tx[s0 * 3 + tid];
    __syncthreads();

    // ---- layer 0: z1 = W0 x + b0 (K=3, fp32 VALU); rows: h | sg*W0[:,1] | sg*W0[:,2]
    {
        int n = tid;  // one output neuron per thread
        float w0 = W0[n * 3 + 0], w1 = W0[n * 3 + 1], w2 = W0[n * 3 + 2], bb = b0v[n];
        #pragma unroll 4
        for (int s = 0; s < TM; ++s) {
            float z = fmaf(w0, txb[s * 3], fmaf(w1, txb[s * 3 + 1], fmaf(w2, txb[s * 3 + 2], bb)));
            float h = softplus20(z);
            float sg = 1.f - __expf(-20.f * h);  // sigmoid(20z) via softplus inverse
            stA(ab, s,          n * 2, h);
            stA(ab, TM + s,     n * 2, sg * w1);
            stA(ab, 2 * TM + s, n * 2, sg * w2);
        }
    }
    __syncthreads();

    float sgr[2][4][4];  // sigma regs: [h-msub][nsub][r]

    // ---- layers 1..3: fused GEMM over M_eff=96 rows (h + 2 tangents), N=K=512
    for (int l = 0; l < 3; ++l) {
        const float* Wl = (l == 0) ? W1 : (l == 1) ? W2 : W3;
        const float* bl = (l == 0) ? b1v : (l == 1) ? b2v : b3v;
        const f16x8* wpb = (const f16x8*)wp + (size_t)l * 16 * 32 * 64;

        f32x4 acc[6][4];
        #pragma unroll
        for (int m = 0; m < 6; ++m)
            #pragma unroll
            for (int n = 0; n < 4; ++n)
                acc[m][n] = f32x4{0.f, 0.f, 0.f, 0.f};

        auto loadB = [&](f16x8* dst, int sk) {
            if constexpr (PREP) {
                const f16x8* p = wpb + (size_t)(sk * 32 + wv * 4) * 64 + lane;
                #pragma unroll
                for (int n = 0; n < 4; ++n) dst[n] = p[n * 64];
            } else {
                #pragma unroll
                for (int n = 0; n < 4; ++n) {
                    const float* q = Wl + (size_t)(wv * 64 + n * 16 + l15) * DD + sk * 32 + g16 * 8;
                    float4 u0 = *(const float4*)q;
                    float4 u1 = *(const float4*)(q + 4);
                    f16x8 r;
                    r[0] = (f16)u0.x; r[1] = (f16)u0.y; r[2] = (f16)u0.z; r[3] = (f16)u0.w;
                    r[4] = (f16)u1.x; r[5] = (f16)u1.y; r[6] = (f16)u1.z; r[7] = (f16)u1.w;
                    dst[n] = r;
                }
            }
        };
        // A fragments are loaded per-m and consumed immediately (LDS latency is
        // short and covered by lgkmcnt + 8-wave TLP). Only B (global/L2 stream,
        // long latency) is double-buffered. Keeps arch-VGPR live set ~100 so a
        // 128-arch cap does not spill (round-1/2 lesson: 378 MB scratch traffic).
        auto domfma = [&](const f16x8* bf, int sk) {
            #pragma unroll
            for (int m = 0; m < 6; ++m) {
                f16x8 a = ldA8(ab, m * 16 + l15, sk * 64 + g16 * 16);
                #pragma unroll
                for (int n = 0; n < 4; ++n)
                    acc[m][n] = __builtin_amdgcn_mfma_f32_16x16x32_f16(a, bf[n], acc[m][n], 0, 0, 0);
            }
        };

        f16x8 bf0[4], bf1[4];
        loadB(bf0, 0);
        for (int sk = 0; sk < 16; sk += 2) {
            loadB(bf1, sk + 1);
            domfma(bf0, sk);
            if (sk + 2 < 16) loadB(bf0, sk + 2);
            domfma(bf1, sk + 1);
        }

        __syncthreads();  // all waves done reading abuf

        float bias[4];
        #pragma unroll
        for (int n = 0; n < 4; ++n) bias[n] = bl[wv * 64 + n * 16 + l15];

        // h rows (msub 0,1): z -> h -> LDS ; sigma -> regs
        #pragma unroll
        for (int m = 0; m < 2; ++m)
            #pragma unroll
            for (int n = 0; n < 4; ++n)
                #pragma unroll
                for (int r = 0; r < 4; ++r) {
                    int row = m * 16 + g16 * 4 + r;
                    float z = acc[m][n][r] + bias[n];
                    float h = softplus20(z);
                    sgr[m][n][r] = 1.f - __expf(-20.f * h);
                    stA(ab, row, (wv * 64 + n * 16 + l15) * 2, h);
                }
        // tangent rows (msub 2..5): hdot = sigma * zdot  (no bias). Same lane/reg as its h.
        #pragma unroll
        for (int m = 2; m < 6; ++m)
            #pragma unroll
            for (int n = 0; n < 4; ++n)
                #pragma unroll
                for (int r = 0; r < 4; ++r) {
                    int row = m * 16 + g16 * 4 + r;
                    float v = sgr[m & 1][n][r] * acc[m][n][r];
                    stA(ab, row, (wv * 64 + n * 16 + l15) * 2, v);
                }
        __syncthreads();
    }

    // ---- final layer (fp32 VALU dots): p = W4[1].h4 + b4[1]; u = (sy_dot, -sx_dot)
    {
        const int kb = lane * 8;
        float wsr[8], wpr[8];
        #pragma unroll
        for (int j = 0; j < 8; ++j) { wsr[j] = W4[kb + j]; wpr[j] = W4[DD + kb + j]; }
        float bp = b4v[1];
        #pragma unroll
        for (int i = 0; i < 4; ++i) {
            int s = wv * 4 + i;
            f16x8 hh = ldA8(ab, s,      lane * 16);
            f16x8 hx = ldA8(ab, 32 + s, lane * 16);
            f16x8 hy = ldA8(ab, 64 + s, lane * 16);
            float dy = 0.f, dx = 0.f, dp = 0.f;
            #pragma unroll
            for (int j = 0; j < 8; ++j) {
                dy = fmaf(wsr[j], (float)hy[j], dy);
                dx = fmaf(wsr[j], (float)hx[j], dx);
                dp = fmaf(wpr[j], (float)hh[j], dp);
            }
            #pragma unroll
            for (int mk = 1; mk < 64; mk <<= 1) {
                dy += __shfl_xor(dy, mk);
                dx += __shfl_xor(dx, mk);
                dp += __shfl_xor(dp, mk);
            }
            if (lane == 0) {
                float* o = out + (s0 + s) * 3;
                o[0] = dy;        // ds/dy
                o[1] = -dx;       // -ds/dx
                o[2] = dp + bp;   // pressure
            }
        }
    }
}

extern "C" void kernel_launch(void* const* d_in, const int* in_sizes, int n_in,
                              void* d_out, int out_size, void* d_ws, size_t ws_size,
                              hipStream_t stream) {
    const float* tx = (const float*)d_in[0];
    const float* W0 = (const float*)d_in[1]; const float* b0 = (const float*)d_in[2];
    const float* W1 = (const float*)d_in[3]; const float* b1 = (const float*)d_in[4];
    const float* W2 = (const float*)d_in[5]; const float* b2 = (const float*)d_in[6];
    const float* W3 = (const float*)d_in[7]; const float* b3 = (const float*)d_in[8];
    const float* W4 = (const float*)d_in[9]; const float* b4 = (const float*)d_in[10];
    float* out = (float*)d_out;

    const size_t need = (size_t)3 * 512 * 512 * sizeof(f16);
    if (ws_size >= need) {
        f16* wp = (f16*)d_ws;
        prep_w<<<(3 * 16 * 32 * 64 + 255) / 256, 256, 0, stream>>>(W1, W2, W3, wp);
        mlp_fused<true><<<NBLK, 512, 0, stream>>>(tx, W0, b0, W1, b1, W2, b2, W3, b3, W4, b4, wp, out);
    } else {
        mlp_fused<false><<<NBLK, 512, 0, stream>>>(tx, W0, b0, W1, b1, W2, b2, W3, b3, W4, b4, nullptr, out);
    }
}